// Round 1
// baseline (283.723 us; speedup 1.0000x reference)
//
#include <hip/hip_runtime.h>

// x: (b=32, t=24, d=10, m=64, n=128) fp32
// out: (b=32, s=12, 1, m=64, n=128) fp32
// One thread per (b, m, n) site: load 24-wide window, run 12-step linear
// EMA recurrence fully in registers, store 12 predictions.

#define B 32
#define T 24
#define D 10
#define M 64
#define N 128
#define S_OUT 12
#define MN (M * N)                  // 8192
#define IN_T_STRIDE (D * MN)        // 81920
#define IN_B_STRIDE (T * D * MN)    // 1966080
#define OUT_B_STRIDE (S_OUT * MN)   // 98304

__global__ __launch_bounds__(256) void moving_avg_kernel(
    const float* __restrict__ x, float* __restrict__ out) {
  const int tid = blockIdx.x * blockDim.x + threadIdx.x;  // 0 .. 262143
  const int mn = tid & (MN - 1);
  const int b  = tid >> 13;  // tid / 8192

  // EMA coefficients: mu = 2/(T+1) = 0.08, q = 0.92
  //   base = q^(T-1)/T ; c[j] = base + (j < T-1 ? mu * q^(T-2-j) : 0)
  const float mu = 2.0f / (T + 1);
  const float q  = 1.0f - mu;  // 0.92
  float c[T];
  {
    float pw = 1.0f;  // q^0
    // build q^(T-1) while filling rec terms from j=T-2 down to 0
    float rec[T];     // temp in registers, fully unrolled
#pragma unroll
    for (int k = 0; k < T - 1; ++k) {
      // at k: pw == q^k ; assign rec for j = T-2-k
      rec[T - 2 - k] = mu * pw;
      pw *= q;
    }
    const float base = pw / (float)T;  // q^(T-1)/T
#pragma unroll
    for (int j = 0; j < T - 1; ++j) c[j] = base + rec[j];
    c[T - 1] = base;
  }

  // Load the 24-element window for this (b, m, n): coalesced along n.
  const float* xp = x + (long)b * IN_B_STRIDE + mn;  // d = 0 slice
  float w[T];
#pragma unroll
  for (int t = 0; t < T; ++t) w[t] = xp[(long)t * IN_T_STRIDE];

  float* op = out + (long)b * OUT_B_STRIDE + mn;
#pragma unroll
  for (int s = 0; s < S_OUT; ++s) {
    float pred = 0.0f;
#pragma unroll
    for (int j = 0; j < T; ++j) pred = fmaf(w[j], c[j], pred);
#pragma unroll
    for (int j = 0; j < T - 1; ++j) w[j] = w[j + 1];
    w[T - 1] = pred;
    op[(long)s * MN] = pred;
  }
}

extern "C" void kernel_launch(void* const* d_in, const int* in_sizes, int n_in,
                              void* d_out, int out_size, void* d_ws, size_t ws_size,
                              hipStream_t stream) {
  const float* x = (const float*)d_in[0];
  float* out = (float*)d_out;
  const int total = B * MN;  // 262144 threads
  moving_avg_kernel<<<total / 256, 256, 0, stream>>>(x, out);
}